// Round 4
// baseline (247.425 us; speedup 1.0000x reference)
//
#include <hip/hip_runtime.h>
#include <hip/hip_bf16.h>

typedef __bf16 bf16_t;
typedef _Float16 f16_t;
typedef bf16_t bf16x8 __attribute__((ext_vector_type(8)));
typedef f16_t  f16x8  __attribute__((ext_vector_type(8)));
typedef f16_t  f16x4  __attribute__((ext_vector_type(4)));
typedef float  floatx4 __attribute__((ext_vector_type(4)));
typedef float  floatx16 __attribute__((ext_vector_type(16)));
typedef bf16x8 bf16x8u __attribute__((aligned(8)));
typedef f16x8  f16x8u  __attribute__((aligned(8)));

#define DEV static __device__ __forceinline__

DEV floatx4 mfma16_bf16(bf16x8 a, bf16x8 b, floatx4 c) {
  return __builtin_amdgcn_mfma_f32_16x16x32_bf16(a, b, c, 0, 0, 0);
}
DEV floatx4 mfma16_f16(f16x8 a, f16x8 b, floatx4 c) {
  return __builtin_amdgcn_mfma_f32_16x16x32_f16(a, b, c, 0, 0, 0);
}
DEV floatx4 mfma16x16_f16(f16x4 a, f16x4 b, floatx4 c) {
  return __builtin_amdgcn_mfma_f32_16x16x16f16(a, b, c, 0, 0, 0);
}
DEV void async_ld16(void* lds, const void* g) {
  __builtin_amdgcn_global_load_lds(
      (const __attribute__((address_space(1))) unsigned int*)g,
      (__attribute__((address_space(3))) unsigned int*)lds, 16, 0, 0);
}
DEV float fast_exp2(float x) {  // v_exp_f32 = 2^x, no libm slow path
  float r;
  asm("v_exp_f32 %0, %1" : "=v"(r) : "v"(x));
  return r;
}

// ---------------------------------------------------------------------------
// Prep: LDS-transposed weight prep (coalesced stores). K weights -> bf16 hi/lo
// [n][k] (+lo at +16384 elems); V weights -> f16 [n][k]. Plus t2 gather.
// ---------------------------------------------------------------------------
__global__ void prep_kernel(const float* __restrict__ Wk1, const float* __restrict__ Wk2,
                            const float* __restrict__ Wv1, const float* __restrict__ Wv2,
                            const float* __restrict__ X,
                            bf16_t* __restrict__ W1p, bf16_t* __restrict__ W2p,
                            f16_t* __restrict__ W3f, f16_t* __restrict__ W4f,
                            float* __restrict__ t2pre) {
  int b = blockIdx.x;
  if (b < 16) {
    int m = b >> 2, p = b & 3;   // weight m, k-quarter p (rows k in [32p,32p+32))
    const float* src = m == 0 ? Wk1 : m == 1 ? Wk2 : m == 2 ? Wv1 : Wv2;
    __shared__ float tile[32][129];
    for (int u = 0; u < 4; ++u) {
      int idx = threadIdx.x + u * 256;        // 1024 float4 units
      int k = idx >> 5, n4 = (idx & 31) << 2;
      float4 v = *(const float4*)(src + (size_t)(p * 32 + k) * 128 + n4);
      tile[k][n4 + 0] = v.x; tile[k][n4 + 1] = v.y;
      tile[k][n4 + 2] = v.z; tile[k][n4 + 3] = v.w;
    }
    __syncthreads();
    if (m < 2) {
      bf16_t* dst = m ? W2p : W1p;
      for (int u = 0; u < 2; ++u) {
        int idx = threadIdx.x + u * 256;      // 512 units: n, k-chunk of 8
        int n = idx >> 2, kc = idx & 3;
        bf16x8 hi, lo;
        for (int j = 0; j < 8; ++j) {
          float v = tile[kc * 8 + j][n];
          bf16_t hh = (bf16_t)v;
          hi[j] = hh;
          lo[j] = (bf16_t)(v - (float)hh);
        }
        *(bf16x8*)(dst + n * 128 + p * 32 + kc * 8) = hi;
        *(bf16x8*)(dst + 16384 + n * 128 + p * 32 + kc * 8) = lo;
      }
    } else {
      f16_t* dst = (m == 3) ? W4f : W3f;
      for (int u = 0; u < 2; ++u) {
        int idx = threadIdx.x + u * 256;
        int n = idx >> 2, kc = idx & 3;
        f16x8 w;
        for (int j = 0; j < 8; ++j) w[j] = (f16_t)tile[kc * 8 + j][n];
        *(f16x8*)(dst + n * 128 + p * 32 + kc * 8) = w;
      }
    }
  } else {
    int i = (b - 16) * 256 + threadIdx.x;     // n*1024 + l
    t2pre[i] = X[((size_t)(i >> 10) * 8192 + (i & 1023)) * 128 + 127];
  }
}

// ---------------------------------------------------------------------------
// MLP-K: split-bf16, 64 rows/block, dbuf weight staging (8 phases).
// ---------------------------------------------------------------------------
__global__ __launch_bounds__(256) void mlp_k_kernel(
    const float* __restrict__ X, const float* __restrict__ b1,
    const float* __restrict__ b2, const bf16_t* __restrict__ W1p,
    const bf16_t* __restrict__ W2p, bf16_t* __restrict__ Khi,
    bf16_t* __restrict__ Klo) {
  __shared__ __align__(16) char sXbuf[2 * 16896];
  __shared__ __align__(16) bf16_t sW[2][256 * 40];
  bf16_t* sXh = (bf16_t*)sXbuf;
  bf16_t* sXl = sXh + 64 * 132;

  const int tid = threadIdx.x, lane = tid & 63, wave = tid >> 6;
  const int q = lane >> 4, c15 = lane & 15;
  const size_t rowBase = (size_t)blockIdx.x * 64;

  int goff[5];
  for (int a = 0; a < 5; ++a) {
    int o = (wave + 4 * a) * 1024 + lane * 16;
    int row = o / 80, rem = o % 80;
    goff[a] = row * 256 + (rem < 64 ? rem : 0);
  }
  auto issueW = [&](int buf, int ph) {
    const bf16_t* Wp = (ph < 4) ? W1p : W2p;
    const char* base = (const char*)Wp + (ph & 3) * 64;
    for (int a = 0; a < 5; ++a)
      async_ld16((char*)sW[buf] + (wave + 4 * a) * 1024 + lane * 16, base + goff[a]);
  };

  issueW(0, 0);    // prefetch W phase 0 under X conversion

  float b1v[8], b2v[8];
  for (int nt = 0; nt < 8; ++nt) { b1v[nt] = b1[nt * 16 + c15]; b2v[nt] = b2[nt * 16 + c15]; }

  for (int u = 0; u < 8; ++u) {
    int idx = tid + u * 256;
    int r = idx >> 5, c4 = (idx & 31) << 2;
    float4 v = *(const float4*)(X + (rowBase + r) * 128 + c4);
    int o = r * 132 + c4;
    float vv[4] = {v.x, v.y, v.z, v.w};
    for (int i = 0; i < 4; ++i) {
      bf16_t h = (bf16_t)vv[i];
      sXh[o + i] = h;
      sXl[o + i] = (bf16_t)(vv[i] - (float)h);
    }
  }

  floatx4 acc1[8], acc2[8];
  for (int i = 0; i < 8; ++i) { acc1[i] = {}; acc2[i] = {}; }

  __syncthreads();
#pragma unroll
  for (int ph = 0; ph < 8; ++ph) {
    if (ph < 7) issueW((ph + 1) & 1, ph + 1);
    const bf16_t* wb = sW[ph & 1];
    const int kq = ph & 3;
    floatx4* acc = (ph < 4) ? acc1 : acc2;
    const int ao = (wave * 16 + c15) * 132 + kq * 32 + q * 8;
    bf16x8 ah = *(const bf16x8u*)(sXh + ao);
    bf16x8 al = *(const bf16x8u*)(sXl + ao);
    for (int nt = 0; nt < 8; ++nt) {
      const int bo = (nt * 16 + c15) * 40 + q * 8;
      bf16x8 bh = *(const bf16x8*)(wb + bo);
      bf16x8 bl = *(const bf16x8*)(wb + 128 * 40 + bo);
      acc[nt] = mfma16_bf16(ah, bh, acc[nt]);
      acc[nt] = mfma16_bf16(ah, bl, acc[nt]);
      acc[nt] = mfma16_bf16(al, bh, acc[nt]);
    }
    if (ph == 3) {
      for (int nt = 0; nt < 8; ++nt)
        for (int r = 0; r < 4; ++r) {
          float h = fmaxf(acc1[nt][r] + b1v[nt], 0.f);
          bf16_t hh = (bf16_t)h;
          int o = (wave * 16 + q * 4 + r) * 132 + nt * 16 + c15;
          sXh[o] = hh;
          sXl[o] = (bf16_t)(h - (float)hh);
        }
    }
    __syncthreads();
  }

  for (int nt = 0; nt < 8; ++nt)
    for (int r = 0; r < 4; ++r) {
      float kv = acc2[nt][r] + b2v[nt];
      bf16_t kh = (bf16_t)kv;
      int o = (wave * 16 + q * 4 + r) * 132 + nt * 16 + c15;
      sXh[o] = kh;
      sXl[o] = (bf16_t)(kv - (float)kh);
    }
  __syncthreads();
  for (int u = 0; u < 4; ++u) {
    int idx = tid + u * 256;
    int r = idx >> 4, c8 = (idx & 15) << 3;
    bf16x8 vh = *(const bf16x8u*)(sXh + r * 132 + c8);
    bf16x8 vl = *(const bf16x8u*)(sXl + r * 132 + c8);
    *(bf16x8*)(Khi + (rowBase + r) * 128 + c8) = vh;
    *(bf16x8*)(Klo + (rowBase + r) * 128 + c8) = vl;
  }
}

// ---------------------------------------------------------------------------
// MLP-V: pure f16 (R2-proven numerics), dbuf phases; emits V^T (f16).
// ---------------------------------------------------------------------------
__global__ __launch_bounds__(256) void mlp_v_kernel(
    const float* __restrict__ X, const float* __restrict__ b1,
    const float* __restrict__ b2, const f16_t* __restrict__ W1f,
    const f16_t* __restrict__ W2f, f16_t* __restrict__ Vt) {
  __shared__ __align__(16) f16_t sXf[64 * 136];    // X/H; later V^T [128][68]
  __shared__ __align__(16) f16_t sW[2][128 * 40];

  const int tid = threadIdx.x, lane = tid & 63, wave = tid >> 6;
  const int q = lane >> 4, c15 = lane & 15;
  const size_t rowBase = (size_t)blockIdx.x * 64;

  int goff[3];
  for (int a = 0; a < 3; ++a) {
    int o = (wave + 4 * a) * 1024 + lane * 16;
    int row = o / 80, rem = o % 80;
    goff[a] = row * 256 + (rem < 64 ? rem : 0);
  }
  auto issueV = [&](int buf, int ph) {
    const f16_t* Wp = (ph < 4) ? W1f : W2f;
    const char* base = (const char*)Wp + (ph & 3) * 64;
    for (int a = 0; a < 3; ++a) {
      int j = wave + 4 * a;
      if (j < 10) async_ld16((char*)sW[buf] + j * 1024 + lane * 16, base + goff[a]);
    }
  };

  issueV(0, 0);

  float b1v[8], bvv[2][4];
  for (int nt = 0; nt < 8; ++nt) b1v[nt] = b1[nt * 16 + c15];
  for (int mt = 0; mt < 2; ++mt)
    for (int r = 0; r < 4; ++r)
      bvv[mt][r] = b2[(wave * 2 + mt) * 16 + q * 4 + r];

  for (int u = 0; u < 8; ++u) {
    int idx = tid + u * 256;
    int r = idx >> 5, c4 = (idx & 31) << 2;
    float4 v = *(const float4*)(X + (rowBase + r) * 128 + c4);
    int o = r * 136 + c4;
    sXf[o + 0] = (f16_t)v.x; sXf[o + 1] = (f16_t)v.y;
    sXf[o + 2] = (f16_t)v.z; sXf[o + 3] = (f16_t)v.w;
  }

  floatx4 acc1[8], acc2[2][4];
  for (int i = 0; i < 8; ++i) acc1[i] = {};
  for (int i = 0; i < 2; ++i) for (int j = 0; j < 4; ++j) acc2[i][j] = {};

  __syncthreads();
#pragma unroll
  for (int ph = 0; ph < 8; ++ph) {
    if (ph < 7) issueV((ph + 1) & 1, ph + 1);
    const f16_t* wb = sW[ph & 1];
    const int kq = ph & 3;
    if (ph < 4) {
      f16x8 a = *(const f16x8u*)(sXf + (wave * 16 + c15) * 136 + kq * 32 + q * 8);
      for (int nt = 0; nt < 8; ++nt) {
        f16x8 bb = *(const f16x8*)(wb + (nt * 16 + c15) * 40 + q * 8);
        acc1[nt] = mfma16_f16(a, bb, acc1[nt]);
      }
      if (ph == 3) {
        for (int nt = 0; nt < 8; ++nt)
          for (int r = 0; r < 4; ++r)
            sXf[(wave * 16 + q * 4 + r) * 136 + nt * 16 + c15] =
                (f16_t)fmaxf(acc1[nt][r] + b1v[nt], 0.f);
      }
    } else {
      f16x8 aw0 = *(const f16x8*)(wb + ((wave * 2 + 0) * 16 + c15) * 40 + q * 8);
      f16x8 aw1 = *(const f16x8*)(wb + ((wave * 2 + 1) * 16 + c15) * 40 + q * 8);
      for (int nt = 0; nt < 4; ++nt) {
        f16x8 bh = *(const f16x8u*)(sXf + (nt * 16 + c15) * 136 + kq * 32 + q * 8);
        acc2[0][nt] = mfma16_f16(aw0, bh, acc2[0][nt]);
        acc2[1][nt] = mfma16_f16(aw1, bh, acc2[1][nt]);
      }
    }
    __syncthreads();
  }

  f16_t* sVT = sXf;   // [128][68] f16
  for (int mt = 0; mt < 2; ++mt)
    for (int nt = 0; nt < 4; ++nt)
      for (int r = 0; r < 4; ++r) {
        int c = (wave * 2 + mt) * 16 + q * 4 + r;
        sVT[c * 68 + nt * 16 + c15] = (f16_t)(acc2[mt][nt][r] + bvv[mt][r]);
      }
  __syncthreads();
  const int nh = (int)(rowBase >> 10);
  const int lB = (int)(rowBase & 1023);
  for (int u = 0; u < 4; ++u) {
    int idx = tid + u * 256;
    int c = idx >> 3, l8 = (idx & 7) << 3;
    *(f16x8*)(Vt + ((size_t)nh * 128 + c) * 1024 + lB + l8) =
        *(const f16x8u*)(sVT + c * 68 + l8);
  }
}

// ---------------------------------------------------------------------------
// attn: 16-row waves via 16x16 MFMA -> 4096 waves total = 16 waves/CU =
// 4 waves/SIMD (2x the latency-hiding of the 32-row/mfma32 structure, whose
// 2048-wave total capped the machine at 2 waves/SIMD). 512 blocks x 8 waves
// (128 rows/block), 2 blocks/CU. Triple-buffered 32-L tiles, distance-2
// prefetch, counted vmcnt(3) (3 chunks/wave/batch). K source-XOR-swizzled
// 16B units (g = s ^ (row&15)); V^T 64B rows with 16B-unit swizzle
// u ^ (d&3) (global-side pre-permute, rule #21) -> b64 reads at the
// 4-lane/bank-pair floor. PV uses mfma_f32_16x16x16_f16 whose B-frag
// layout (n=lane&15, k=(lane>>4)*4+j) exactly matches the S C/D frag ->
// P feeds PV with zero cross-lane shuffles.
// ---------------------------------------------------------------------------
__global__ __launch_bounds__(512, 4) void attn_kernel(
    const float* __restrict__ Q, const float* __restrict__ t1,
    const float* __restrict__ t2pre, const float* __restrict__ ltau,
    const bf16_t* __restrict__ Khi, const bf16_t* __restrict__ Klo,
    const f16_t* __restrict__ Vt, float* __restrict__ out) {
  // per buffer: [K hi 8192 | K lo 8192 | V 8192] = 24576 B
  __shared__ __align__(16) char sBuf[3][24576];
  __shared__ __align__(16) float sT2[1024];

  const int tid = threadIdx.x, lane = tid & 63, wave = tid >> 6;
  const int q = lane >> 4, r15 = lane & 15;
  const int nh = blockIdx.x & 63;                  // same-head blocks share XCD slot
  const int seg = blockIdx.x >> 6;                 // 0..7: 128-row segment
  const int n = nh >> 3;
  const int qbase = seg * 128 + wave * 16;
  const float negc2 = -__expf(-ltau[0]) * 1.44269504f;

  // 24 chunks: 16 K + 8 V, 3 per wave -> uniform vmcnt accounting, no dups
  const char* gp[3]; int ls[3]; int st[3];
  for (int a = 0; a < 3; ++a) {
    int j = wave + 8 * a;                          // 0..23
    if (j < 16) {                                  // K: swizzled global source
      int o = j * 1024 + lane * 16;
      int half = o >> 13;
      int r2 = o & 8191;
      int row = r2 >> 8;
      int s = (r2 >> 4) & 15;
      int g = s ^ (row & 15);                      // XOR-swizzle on GLOBAL side
      gp[a] = (const char*)(half ? Klo : Khi) +
              ((size_t)((nh << 10) + row)) * 256 + (g << 4);
      st[a] = 8192; ls[a] = o;
    } else {                                       // V: 64B rows, 16B-unit swizzle
      int o = (j - 16) * 1024 + lane * 16;         // 0..8191
      int d = o >> 6;                              // V^T row (column of V)
      int u = (o >> 4) & 3;                        // 16B unit within row
      int up = u ^ (d & 3);                        // pre-permute global source
      gp[a] = (const char*)Vt + ((size_t)((nh << 7) + d)) * 2048 + (up << 4);
      st[a] = 64; ls[a] = 16384 + o;
    }
  }
  auto stage = [&](int buf) {
    for (int a = 0; a < 3; ++a) { async_ld16(sBuf[buf] + ls[a], gp[a]); gp[a] += st[a]; }
  };

  // t2 -> LDS (one-time), Q loads (16 rows/wave: row = qbase + r15), prime 2
  float2 t2v2 = *(const float2*)(t2pre + (n << 10) + tid * 2);
  const float t1v = t1[(n << 10) + qbase + r15];
  bf16x8 qh[4], ql[4];
  {
    const float* qr = Q + ((size_t)(nh << 10) + qbase + r15) * 128;
    for (int kq = 0; kq < 4; ++kq) {
      const float* p = qr + kq * 32 + q * 8;       // B-frag: k = kq*32 + q*8 + j
      float4 v0 = *(const float4*)p;
      float4 v1 = *(const float4*)(p + 4);
      float vv[8] = {v0.x, v0.y, v0.z, v0.w, v1.x, v1.y, v1.z, v1.w};
      bf16x8 hi, lo;
      for (int j = 0; j < 8; ++j) {
        bf16_t hj = (bf16_t)vv[j];
        hi[j] = hj;
        lo[j] = (bf16_t)(vv[j] - (float)hj);
      }
      qh[kq] = hi;
      ql[kq] = lo;
    }
  }
  stage(0);
  stage(1);
  *(float2*)(sT2 + tid * 2) = t2v2;

  floatx4 O[8];
  for (int i = 0; i < 8; ++i) O[i] = {};
  float ds = 0.f;

  // gate: batch 0 done (3 newer = batch 1 in flight), t2 ds_write done
  asm volatile("s_waitcnt vmcnt(3) lgkmcnt(0)" ::: "memory");
  __builtin_amdgcn_s_barrier();
  asm volatile("" ::: "memory");

  for (int it = 0; it < 32; ++it) {
    if (it <= 29) stage((it + 2) % 3);
    const char* kb = sBuf[it % 3];
    const char* vb = kb + 16384;

    // QK^T: Sa = L 0..15, Sb = L 16..31; two independent 12-chains
    floatx4 Sa = {}, Sb = {};
    __builtin_amdgcn_s_setprio(1);
#pragma unroll
    for (int kq = 0; kq < 4; ++kq) {
      const int un = (((kq << 2) + q) ^ r15) << 4;
      const int boA = r15 * 256 + un;
      const int boB = (16 + r15) * 256 + un;
      bf16x8 kha = *(const bf16x8*)(kb + boA);
      bf16x8 kla = *(const bf16x8*)(kb + 8192 + boA);
      bf16x8 khb = *(const bf16x8*)(kb + boB);
      bf16x8 klb = *(const bf16x8*)(kb + 8192 + boB);
      Sa = mfma16_bf16(kha, qh[kq], Sa);
      Sa = mfma16_bf16(kla, qh[kq], Sa);
      Sa = mfma16_bf16(kha, ql[kq], Sa);
      Sb = mfma16_bf16(khb, qh[kq], Sb);
      Sb = mfma16_bf16(klb, qh[kq], Sb);
      Sb = mfma16_bf16(khb, ql[kq], Sb);
    }
    __builtin_amdgcn_s_setprio(0);

    // softmax + PV per 16-L chunk; lane holds S[L=c1*16+4q+j][qrow=r15]
    const float* t2b = sT2 + it * 32 + 4 * q;
#pragma unroll
    for (int c1 = 0; c1 < 2; ++c1) {
      floatx4 Sv = c1 ? Sb : Sa;
      float4 tv4 = *(const float4*)(t2b + c1 * 16);
      float tv[4] = {tv4.x, tv4.y, tv4.z, tv4.w};
      f16x4 pb;
      for (int j = 0; j < 4; ++j) {
        float s = Sv[j];
        float e = fast_exp2(s * s * negc2);
        bool m = (t1v >= tv[j]);
        ds += m ? e : 1.f;
        pb[j] = (f16_t)(m ? e : 0.f);
      }
      const int v = q + (c1 << 2);                 // 8B unit: L-offset/4 within row
      const int vo = (((v >> 1) ^ (r15 & 3)) << 4) + ((v & 1) << 3);
#pragma unroll
      for (int dt = 0; dt < 8; ++dt) {
        f16x4 va = *(const f16x4*)(vb + (dt * 16 + r15) * 64 + vo);
        O[dt] = mfma16x16_f16(va, pb, O[dt]);
      }
    }

    // retire the batch the NEXT iteration reads; newest stays in flight
    if (it <= 29) {
      asm volatile("s_waitcnt vmcnt(3)" ::: "memory");
    } else if (it == 30) {
      asm volatile("s_waitcnt vmcnt(0)" ::: "memory");
    }
    if (it < 31) {
      asm volatile("" ::: "memory");
      __builtin_amdgcn_s_barrier();
      asm volatile("" ::: "memory");
    }
  }

  // denominator: sum over q-groups holding the same q-row (lanes r15+16k)
  ds += __shfl_xor(ds, 16);
  ds += __shfl_xor(ds, 32);
  const float inv = 1.f / ds;
  float* orow = out + ((size_t)(nh << 10) + qbase + r15) * 128;
#pragma unroll
  for (int dt = 0; dt < 8; ++dt) {
    float4 v = {O[dt][0] * inv, O[dt][1] * inv, O[dt][2] * inv, O[dt][3] * inv};
    *(float4*)(orow + dt * 16 + 4 * q) = v;        // d = dt*16 + 4q + reg
  }
}

extern "C" void kernel_launch(void* const* d_in, const int* in_sizes, int n_in,
                              void* d_out, int out_size, void* d_ws, size_t ws_size,
                              hipStream_t stream) {
  const float* X   = (const float*)d_in[0];
  const float* t1  = (const float*)d_in[1];
  const float* Q   = (const float*)d_in[2];
  const float* Wk1 = (const float*)d_in[3];
  const float* bk1 = (const float*)d_in[4];
  const float* Wk2 = (const float*)d_in[5];
  const float* bk2 = (const float*)d_in[6];
  const float* Wv1 = (const float*)d_in[7];
  const float* bv1 = (const float*)d_in[8];
  const float* Wv2 = (const float*)d_in[9];
  const float* bv2 = (const float*)d_in[10];
  const float* log_tau = (const float*)d_in[11];
  float* out = (float*)d_out;

  const size_t E = (size_t)64 * 1024 * 128;
  bf16_t* Khi = (bf16_t*)d_ws;
  bf16_t* Klo = Khi + E;
  f16_t*  Vt  = (f16_t*)(Klo + E);
  bf16_t* W1p = (bf16_t*)((char*)d_ws + 3 * E * 2);
  bf16_t* W2p = W1p + 32768;
  f16_t*  W3f = (f16_t*)(W2p + 32768);
  f16_t*  W4f = W3f + 16384;
  float*  t2pre = (float*)(W4f + 16384);

  prep_kernel<<<48, 256, 0, stream>>>(Wk1, Wk2, Wv1, Wv2, X, W1p, W2p, W3f, W4f, t2pre);
  mlp_k_kernel<<<1024, 256, 0, stream>>>(X, bk1, bk2, W1p, W2p, Khi, Klo);
  mlp_v_kernel<<<1024, 256, 0, stream>>>(X, bv1, bv2, W3f, W4f, Vt);
  attn_kernel<<<512, 512, 0, stream>>>(Q, t1, t2pre, log_tau, Khi, Klo, Vt, out);
}